// Round 4
// baseline (781.451 us; speedup 1.0000x reference)
//
#include <hip/hip_runtime.h>
#include <hip/hip_cooperative_groups.h>

namespace cg = cooperative_groups;

#define E_EDGES 131072
#define N_NODES 4096
#define HOUT    64
#define NE_TOT  (4 * E_EDGES)
#define CAP     256            // per-row slot capacity (mean deg 128, ~11 sigma headroom)
#define NBLK    1024
#define NTHR    256

// ---------------------------------------------------------------- helpers
__device__ __forceinline__ void softmax4(const float* __restrict__ cw,
                                         int layer, int c, float f[4]) {
#pragma unroll
    for (int t = 0; t < 4; ++t) f[t] = cw[(layer * 2 + c) * 4 + t];
    float m = fmaxf(fmaxf(f[0], f[1]), fmaxf(f[2], f[3]));
    float s = 0.f;
#pragma unroll
    for (int t = 0; t < 4; ++t) { f[t] = expf(f[t] - m); s += f[t]; }
    float inv = 1.0f / s;
#pragma unroll
    for (int t = 0; t < 4; ++t) f[t] *= inv;
}

__device__ __forceinline__ float selw(const float f[4], int t) {
    float a = (t & 1) ? f[1] : f[0];
    float b = (t & 1) ? f[3] : f[2];
    return (t & 2) ? b : a;
}

// wave-level SpMM over one row's slot [erow, erow+len): 4 edges per step
// (one per 16-lane group), lane gathers a float4 quarter-row; 4x unrolled.
__device__ __forceinline__ float4 spmm_row(const uint2* __restrict__ erow, int len,
                                           const float* __restrict__ Hc,
                                           const float f[4], int lane) {
    int g  = lane >> 4;
    int hq = lane & 15;
    float4 acc = make_float4(0.f, 0.f, 0.f, 0.f);
    int e = 0;
    for (; e + 16 <= len; e += 16) {
        uint2 r0 = erow[e + g];
        uint2 r1 = erow[e + 4 + g];
        uint2 r2 = erow[e + 8 + g];
        uint2 r3 = erow[e + 12 + g];
        float w0 = __uint_as_float(r0.y) * selw(f, (int)(r0.x >> 16));
        float w1 = __uint_as_float(r1.y) * selw(f, (int)(r1.x >> 16));
        float w2 = __uint_as_float(r2.y) * selw(f, (int)(r2.x >> 16));
        float w3 = __uint_as_float(r3.y) * selw(f, (int)(r3.x >> 16));
        float4 v0 = ((const float4*)(Hc + (r0.x & 0xFFFF) * HOUT))[hq];
        float4 v1 = ((const float4*)(Hc + (r1.x & 0xFFFF) * HOUT))[hq];
        float4 v2 = ((const float4*)(Hc + (r2.x & 0xFFFF) * HOUT))[hq];
        float4 v3 = ((const float4*)(Hc + (r3.x & 0xFFFF) * HOUT))[hq];
        acc.x += w0 * v0.x; acc.y += w0 * v0.y; acc.z += w0 * v0.z; acc.w += w0 * v0.w;
        acc.x += w1 * v1.x; acc.y += w1 * v1.y; acc.z += w1 * v1.z; acc.w += w1 * v1.w;
        acc.x += w2 * v2.x; acc.y += w2 * v2.y; acc.z += w2 * v2.z; acc.w += w2 * v2.w;
        acc.x += w3 * v3.x; acc.y += w3 * v3.y; acc.z += w3 * v3.z; acc.w += w3 * v3.w;
    }
    for (; e + 4 <= len; e += 4) {
        uint2 r0 = erow[e + g];
        float w0 = __uint_as_float(r0.y) * selw(f, (int)(r0.x >> 16));
        float4 v0 = ((const float4*)(Hc + (r0.x & 0xFFFF) * HOUT))[hq];
        acc.x += w0 * v0.x; acc.y += w0 * v0.y; acc.z += w0 * v0.z; acc.w += w0 * v0.w;
    }
    if (g < len - e) {
        uint2 r0 = erow[e + g];
        float w0 = __uint_as_float(r0.y) * selw(f, (int)(r0.x >> 16));
        float4 v0 = ((const float4*)(Hc + (r0.x & 0xFFFF) * HOUT))[hq];
        acc.x += w0 * v0.x; acc.y += w0 * v0.y; acc.z += w0 * v0.z; acc.w += w0 * v0.w;
    }
    acc.x += __shfl_xor(acc.x, 16); acc.y += __shfl_xor(acc.y, 16);
    acc.z += __shfl_xor(acc.z, 16); acc.w += __shfl_xor(acc.w, 16);
    acc.x += __shfl_xor(acc.x, 32); acc.y += __shfl_xor(acc.y, 32);
    acc.z += __shfl_xor(acc.z, 32); acc.w += __shfl_xor(acc.w, 32);
    return acc;
}

// ---------------------------------------------------------------- phases
__device__ void phase_zero_init(const float* __restrict__ X,
                                const float* __restrict__ Ws,
                                float* __restrict__ H0,
                                int* __restrict__ cursor) {
    int tid = blockIdx.x * NTHR + threadIdx.x;
    int nt  = gridDim.x * NTHR;
    if (tid < N_NODES) cursor[tid] = 0;
    for (int idx = tid; idx < 2 * N_NODES * HOUT; idx += nt) {
        int h = idx & 63;
        int n = (idx >> 6) & (N_NODES - 1);
        int c = idx >> 18;
        const float4* xv = (const float4*)(X + n * 128);
        const float*  w  = Ws + c * 128 * HOUT + h;
        float acc = 0.f;
#pragma unroll 8
        for (int k4 = 0; k4 < 32; ++k4) {
            float4 xx = xv[k4];
            acc += xx.x * w[(k4 * 4 + 0) * HOUT];
            acc += xx.y * w[(k4 * 4 + 1) * HOUT];
            acc += xx.z * w[(k4 * 4 + 2) * HOUT];
            acc += xx.w * w[(k4 * 4 + 3) * HOUT];
        }
        H0[idx] = acc;
    }
}

__device__ void phase_scatter(const int* __restrict__ ei,
                              const float* __restrict__ ew,
                              int* __restrict__ cursor,
                              uint2* __restrict__ edges) {
    int tid = blockIdx.x * NTHR + threadIdx.x;
    int nt  = gridDim.x * NTHR;
    for (int i = tid; i < NE_TOT; i += nt) {
        int t = i >> 17;
        int e = i & (E_EDGES - 1);
        int src = ei[(t * 2 + 0) * E_EDGES + e];
        int dst = ei[(t * 2 + 1) * E_EDGES + e];
        float w = ew[t * E_EDGES + e];
        int pos = atomicAdd(&cursor[src], 1);
        edges[src * CAP + pos] = make_uint2((unsigned)dst | ((unsigned)t << 16),
                                            __float_as_uint(w));
    }
}

__device__ void phase_spmm(const int* __restrict__ cnt,
                           const uint2* __restrict__ edges,
                           const float* __restrict__ Hin,
                           float* __restrict__ Hout,
                           const float* __restrict__ cw) {
    int wave  = (blockIdx.x * NTHR + threadIdx.x) >> 6;
    int lane  = threadIdx.x & 63;
    int nwave = (gridDim.x * NTHR) >> 6;
    for (int task = wave; task < 2 * N_NODES; task += nwave) {
        int row = task >> 1, c = task & 1;
        float f[4]; softmax4(cw, 0, c, f);
        float4 acc = spmm_row(edges + row * CAP, cnt[row],
                              Hin + c * N_NODES * HOUT, f, lane);
        if (lane < 16)
            ((float4*)(Hout + (c * N_NODES + row) * HOUT))[lane] = acc;
    }
}

template <bool FINAL>
__device__ void phase_tail(const int* __restrict__ cnt,
                           const uint2* __restrict__ edges,
                           const float* __restrict__ Hin,
                           const float* __restrict__ H0,
                           const float* __restrict__ cw,
                           const float* __restrict__ lw,
                           const float* __restrict__ lb,
                           const float* __restrict__ Wsn,
                           float* __restrict__ outp) {
    __shared__ float h2s[2][128];
    __shared__ float hcomb[2][128];
    __shared__ float mids[2][64];
    int lt   = threadIdx.x;        // 256 threads = 4 waves: (half, c)
    int wave = lt >> 6;
    int half = wave >> 1;
    int c    = wave & 1;
    int lane = lt & 63;
    float f[4]; softmax4(cw, 1, c, f);
    for (int pair = blockIdx.x; pair < N_NODES / 2; pair += gridDim.x) {
        int row = pair * 2 + half;
        float4 acc = spmm_row(edges + row * CAP, cnt[row],
                              Hin + c * N_NODES * HOUT, f, lane);
        if (lane < 16) ((float4*)&h2s[half][c * HOUT])[lane] = acc;
        __syncthreads();
        float h0v = H0[(c * N_NODES + row) * HOUT + lane];
        hcomb[half][c * HOUT + lane] =
            fmaxf(0.1f * h0v + 0.9f * h2s[half][c * HOUT + lane], 0.f);
        __syncthreads();
        if (FINAL) {
            if (c == 0) {
                float a = lb[lane];
#pragma unroll 8
                for (int j = 0; j < 128; ++j) a += hcomb[half][j] * lw[j * HOUT + lane];
                outp[row * HOUT + lane] = fmaxf(a, 0.f);
            }
        } else {
            if (c == 0) {
                float a = lb[lane];
#pragma unroll 8
                for (int j = 0; j < 128; ++j) a += hcomb[half][j] * lw[j * HOUT + lane];
                mids[half][lane] = fmaxf(a, 0.f);
            }
            __syncthreads();
            float a = 0.f;
            const float* w = Wsn + c * HOUT * HOUT + lane;
#pragma unroll 8
            for (int k = 0; k < HOUT; ++k) a += mids[half][k] * w[k * HOUT];
            outp[(c * N_NODES + row) * HOUT + lane] = a;
        }
        __syncthreads();
    }
}

// ---------------------------------------------------------------- mega
__global__ void __launch_bounds__(NTHR, 4)
mega_kernel(const int* ei, const float* ew, const float* X,
            const float* Ws1, const float* cw1, const float* lw1, const float* lb1,
            const float* Ws2, const float* cw2, const float* lw2, const float* lb2,
            int* cursor, uint2* edges, float* H0a, float* Ha, float* H0b,
            float* outp) {
    cg::grid_group grid = cg::this_grid();
    phase_zero_init(X, Ws1, H0a, cursor);
    grid.sync();
    phase_scatter(ei, ew, cursor, edges);
    grid.sync();
    phase_spmm(cursor, edges, H0a, Ha, cw1);
    grid.sync();
    phase_tail<false>(cursor, edges, Ha, H0a, cw1, lw1, lb1, Ws2, H0b);
    grid.sync();
    phase_spmm(cursor, edges, H0b, Ha, cw2);
    grid.sync();
    phase_tail<true>(cursor, edges, Ha, H0b, cw2, lw2, lb2, nullptr, outp);
}

// ------------------------------------------------ discrete fallback kernels
__global__ void __launch_bounds__(NTHR)
k_zero_init(const float* X, const float* Ws, float* H0, int* cursor) {
    phase_zero_init(X, Ws, H0, cursor);
}
__global__ void __launch_bounds__(NTHR)
k_scatter(const int* ei, const float* ew, int* cursor, uint2* edges) {
    phase_scatter(ei, ew, cursor, edges);
}
__global__ void __launch_bounds__(NTHR)
k_spmm(const int* cnt, const uint2* edges, const float* Hin, float* Hout,
       const float* cw) {
    phase_spmm(cnt, edges, Hin, Hout, cw);
}
__global__ void __launch_bounds__(NTHR)
k_tail_mid(const int* cnt, const uint2* edges, const float* Hin, const float* H0,
           const float* cw, const float* lw, const float* lb, const float* Wsn,
           float* outp) {
    phase_tail<false>(cnt, edges, Hin, H0, cw, lw, lb, Wsn, outp);
}
__global__ void __launch_bounds__(NTHR)
k_tail_fin(const int* cnt, const uint2* edges, const float* Hin, const float* H0,
           const float* cw, const float* lw, const float* lb, float* outp) {
    phase_tail<true>(cnt, edges, Hin, H0, cw, lw, lb, nullptr, outp);
}

extern "C" void kernel_launch(void* const* d_in, const int* in_sizes, int n_in,
                              void* d_out, int out_size, void* d_ws, size_t ws_size,
                              hipStream_t stream) {
    const int*   ei  = (const int*)d_in[0];
    const float* ew  = (const float*)d_in[1];
    const float* X   = (const float*)d_in[2];
    const float* Ws1 = (const float*)d_in[3];
    const float* cw1 = (const float*)d_in[4];
    const float* lw1 = (const float*)d_in[5];
    const float* lb1 = (const float*)d_in[6];
    const float* Ws2 = (const float*)d_in[7];
    const float* cw2 = (const float*)d_in[8];
    const float* lw2 = (const float*)d_in[9];
    const float* lb2 = (const float*)d_in[10];
    float* outp = (float*)d_out;

    char* ws = (char*)d_ws;
    size_t off = 0;
    auto alloc = [&](size_t bytes) -> void* {
        void* p = ws + off;
        off += (bytes + 255) & ~size_t(255);
        return p;
    };
    int*   cursor = (int*)alloc(N_NODES * 4);
    uint2* edges  = (uint2*)alloc((size_t)N_NODES * CAP * 8);
    float* H0a    = (float*)alloc((size_t)2 * N_NODES * HOUT * 4);
    float* Ha     = (float*)alloc((size_t)2 * N_NODES * HOUT * 4);
    float* H0b    = (float*)alloc((size_t)2 * N_NODES * HOUT * 4);

    void* kargs[] = { (void*)&ei, (void*)&ew, (void*)&X,
                      (void*)&Ws1, (void*)&cw1, (void*)&lw1, (void*)&lb1,
                      (void*)&Ws2, (void*)&cw2, (void*)&lw2, (void*)&lb2,
                      (void*)&cursor, (void*)&edges, (void*)&H0a, (void*)&Ha,
                      (void*)&H0b, (void*)&outp };
    hipError_t err = hipLaunchCooperativeKernel(
        reinterpret_cast<void*>(mega_kernel), dim3(NBLK), dim3(NTHR),
        kargs, 0, stream);
    if (err != hipSuccess) {
        // discrete fallback (same phases, 7 dispatches)
        k_zero_init<<<NBLK, NTHR, 0, stream>>>(X, Ws1, H0a, cursor);
        k_scatter  <<<NBLK, NTHR, 0, stream>>>(ei, ew, cursor, edges);
        k_spmm     <<<NBLK, NTHR, 0, stream>>>(cursor, edges, H0a, Ha, cw1);
        k_tail_mid <<<NBLK, NTHR, 0, stream>>>(cursor, edges, Ha, H0a, cw1, lw1, lb1, Ws2, H0b);
        k_spmm     <<<NBLK, NTHR, 0, stream>>>(cursor, edges, H0b, Ha, cw2);
        k_tail_fin <<<NBLK, NTHR, 0, stream>>>(cursor, edges, Ha, H0b, cw2, lw2, lb2, outp);
    }
}

// Round 5
// 123.390 us; speedup vs baseline: 6.3332x; 6.3332x over previous
//
#include <hip/hip_runtime.h>

#define E_EDGES 131072
#define N_NODES 4096
#define HOUT    64
#define NE_TOT  (4 * E_EDGES)
#define CAP     256            // per-row slot capacity (mean deg 128, ~11 sigma)

// ---------------------------------------------------------------- bf16 utils
__device__ __forceinline__ unsigned short f2bf(float x) {
    unsigned u = __float_as_uint(x);
    return (unsigned short)((u + 0x7FFFu + ((u >> 16) & 1u)) >> 16);   // RNE
}
__device__ __forceinline__ float bf2f(unsigned b) {
    return __uint_as_float(b << 16);
}

// ---------------------------------------------------------------- helpers
__device__ __forceinline__ void softmax4(const float* __restrict__ cw,
                                         int layer, int c, float f[4]) {
#pragma unroll
    for (int t = 0; t < 4; ++t) f[t] = cw[(layer * 2 + c) * 4 + t];
    float m = fmaxf(fmaxf(f[0], f[1]), fmaxf(f[2], f[3]));
    float s = 0.f;
#pragma unroll
    for (int t = 0; t < 4; ++t) { f[t] = expf(f[t] - m); s += f[t]; }
    float inv = 1.0f / s;
#pragma unroll
    for (int t = 0; t < 4; ++t) f[t] *= inv;
}

__device__ __forceinline__ float selw(const float f[4], int t) {
    float a = (t & 1) ? f[1] : f[0];
    float b = (t & 1) ? f[3] : f[2];
    return (t & 2) ? b : a;
}

__device__ __forceinline__ void fma8(float acc[8], float w, uint4 v) {
    acc[0] += w * bf2f(v.x & 0xFFFFu); acc[1] += w * bf2f(v.x >> 16);
    acc[2] += w * bf2f(v.y & 0xFFFFu); acc[3] += w * bf2f(v.y >> 16);
    acc[4] += w * bf2f(v.z & 0xFFFFu); acc[5] += w * bf2f(v.z >> 16);
    acc[6] += w * bf2f(v.w & 0xFFFFu); acc[7] += w * bf2f(v.w >> 16);
}

__device__ __forceinline__ uint4 pack8(const float acc[8]) {
    uint4 r;
    r.x = (unsigned)f2bf(acc[0]) | ((unsigned)f2bf(acc[1]) << 16);
    r.y = (unsigned)f2bf(acc[2]) | ((unsigned)f2bf(acc[3]) << 16);
    r.z = (unsigned)f2bf(acc[4]) | ((unsigned)f2bf(acc[5]) << 16);
    r.w = (unsigned)f2bf(acc[6]) | ((unsigned)f2bf(acc[7]) << 16);
    return r;
}

// wave-level SpMM over one row's slot: 8 edges/step (one per 8-lane group),
// each lane gathers a uint4 = 8 bf16 (group covers the full 128B row = 1 line);
// 2x unrolled = 16 edges in flight; butterfly reduce across groups at the end.
// Result: every lane holds the 8 h-values for h = (lane&7)*8 + j.
__device__ __forceinline__ void spmm_row16(const uint2* __restrict__ erow, int len,
                                           const unsigned* __restrict__ Hc16,
                                           const float f[4], int lane, float acc[8]) {
    int g  = lane >> 3;       // edge slot within step (0..7)
    int hq = lane & 7;        // uint4 slot within the row
#pragma unroll
    for (int j = 0; j < 8; ++j) acc[j] = 0.f;
    int e = 0;
    for (; e + 16 <= len; e += 16) {
        uint2 r0 = erow[e + g];
        uint2 r1 = erow[e + 8 + g];
        float w0 = __uint_as_float(r0.y) * selw(f, (int)(r0.x >> 16));
        float w1 = __uint_as_float(r1.y) * selw(f, (int)(r1.x >> 16));
        uint4 v0 = ((const uint4*)(Hc16 + (r0.x & 0xFFFFu) * (HOUT / 2)))[hq];
        uint4 v1 = ((const uint4*)(Hc16 + (r1.x & 0xFFFFu) * (HOUT / 2)))[hq];
        fma8(acc, w0, v0);
        fma8(acc, w1, v1);
    }
    for (; e + 8 <= len; e += 8) {
        uint2 r0 = erow[e + g];
        float w0 = __uint_as_float(r0.y) * selw(f, (int)(r0.x >> 16));
        uint4 v0 = ((const uint4*)(Hc16 + (r0.x & 0xFFFFu) * (HOUT / 2)))[hq];
        fma8(acc, w0, v0);
    }
    if (g < len - e) {
        uint2 r0 = erow[e + g];
        float w0 = __uint_as_float(r0.y) * selw(f, (int)(r0.x >> 16));
        uint4 v0 = ((const uint4*)(Hc16 + (r0.x & 0xFFFFu) * (HOUT / 2)))[hq];
        fma8(acc, w0, v0);
    }
#pragma unroll
    for (int j = 0; j < 8; ++j) {
        acc[j] += __shfl_xor(acc[j], 8);
        acc[j] += __shfl_xor(acc[j], 16);
        acc[j] += __shfl_xor(acc[j], 32);
    }
}

// ---------------------------------------------- zero cursor + H0 = X @ Ws1
// grid 2048x256: one (c,n,h) per thread
__global__ void __launch_bounds__(256)
zinit_kernel(const float* __restrict__ X, const float* __restrict__ Ws,
             float* __restrict__ H0, unsigned* __restrict__ H016,
             int* __restrict__ cursor) {
    int idx = blockIdx.x * 256 + threadIdx.x;
    if (idx < N_NODES) cursor[idx] = 0;
    int h = idx & 63;
    int n = (idx >> 6) & (N_NODES - 1);
    int c = idx >> 18;
    const float4* xv = (const float4*)(X + n * 128);
    const float*  w  = Ws + c * 128 * HOUT + h;
    float acc = 0.f;
#pragma unroll 8
    for (int k4 = 0; k4 < 32; ++k4) {
        float4 xx = xv[k4];
        acc += xx.x * w[(k4 * 4 + 0) * HOUT];
        acc += xx.y * w[(k4 * 4 + 1) * HOUT];
        acc += xx.z * w[(k4 * 4 + 2) * HOUT];
        acc += xx.w * w[(k4 * 4 + 3) * HOUT];
    }
    H0[idx] = acc;
    ((unsigned short*)H016)[idx] = f2bf(acc);
}

// ---------------------------------------------- slot scatter, 4 edges/thread
__global__ void __launch_bounds__(256)
scatter_kernel(const int* __restrict__ ei, const float* __restrict__ ew,
               int* __restrict__ cursor, uint2* __restrict__ edges) {
    int i4 = (blockIdx.x * 256 + threadIdx.x) * 4;
    int t = i4 >> 17;
    int e = i4 & (E_EDGES - 1);
    int4   srcs = *(const int4*)(ei + (t * 2 + 0) * E_EDGES + e);
    int4   dsts = *(const int4*)(ei + (t * 2 + 1) * E_EDGES + e);
    float4 wts  = *(const float4*)(ew + t * E_EDGES + e);
    unsigned tb = (unsigned)t << 16;
#pragma unroll
    for (int j = 0; j < 4; ++j) {
        int   src = (&srcs.x)[j];
        int   dst = (&dsts.x)[j];
        float w   = (&wts.x)[j];
        int pos = atomicAdd(&cursor[src], 1);
        if (pos < CAP)
            edges[src * CAP + pos] = make_uint2((unsigned)dst | tb, __float_as_uint(w));
    }
}

// ---------------------------------------------- layer-0 SpMM (bf16 in/out)
__global__ void __launch_bounds__(256)
spmm_kernel(const int* __restrict__ cnt, const uint2* __restrict__ edges,
            const unsigned* __restrict__ Hin16, unsigned* __restrict__ Hout16,
            const float* __restrict__ cw) {
    int task = (blockIdx.x * 256 + threadIdx.x) >> 6;   // 8192 = row*2 + c
    int lane = threadIdx.x & 63;
    int row  = task >> 1, c = task & 1;
    float f[4]; softmax4(cw, 0, c, f);
    int len = min(cnt[row], CAP);
    float acc[8];
    spmm_row16(edges + row * CAP, len, Hin16 + c * N_NODES * (HOUT / 2), f, lane, acc);
    if ((lane >> 3) == 0)    // 8 lanes write 8 uint4 = full 128B row
        ((uint4*)(Hout16 + (c * N_NODES + row) * (HOUT / 2)))[lane & 7] = pack8(acc);
}

// ------- layer-1 SpMM + beta-combine + linear (+ next-FastGTN init)
template <bool FINAL>
__global__ void __launch_bounds__(128)
tail_kernel(const int* __restrict__ cnt, const uint2* __restrict__ edges,
            const unsigned* __restrict__ Hin16,   // layer-1 conv input (bf16)
            const float* __restrict__ H0,         // X_ detached init (f32)
            const float* __restrict__ cw,
            const float* __restrict__ lw, const float* __restrict__ lb,
            const float* __restrict__ Wsn,
            float* __restrict__ outp, unsigned* __restrict__ out16) {
    __shared__ float hcomb[2 * HOUT];
    __shared__ float mids[HOUT];
    int tid  = threadIdx.x;       // 128 = 2 waves, wave == channel
    int c    = tid >> 6;
    int lane = tid & 63;
    int row  = blockIdx.x;

    float f[4]; softmax4(cw, 1, c, f);
    int len = min(cnt[row], CAP);
    float acc[8];
    spmm_row16(edges + row * CAP, len, Hin16 + c * N_NODES * (HOUT / 2), f, lane, acc);
    // H_ = relu(0.1*X_ + 0.9*H2): lanes g==0 hold h = hq*8+j
    if ((lane >> 3) == 0) {
        int hq = lane & 7;
#pragma unroll
        for (int j = 0; j < 8; ++j) {
            int h = hq * 8 + j;
            float h0v = H0[(c * N_NODES + row) * HOUT + h];
            hcomb[c * HOUT + h] = fmaxf(0.1f * h0v + 0.9f * acc[j], 0.f);
        }
    }
    __syncthreads();

    if (FINAL) {
        if (tid < 64) {
            float a = lb[tid];
#pragma unroll 8
            for (int j = 0; j < 2 * HOUT; ++j) a += hcomb[j] * lw[j * HOUT + tid];
            outp[row * HOUT + tid] = fmaxf(a, 0.f);
        }
    } else {
        if (tid < 64) {
            float a = lb[tid];
#pragma unroll 8
            for (int j = 0; j < 2 * HOUT; ++j) a += hcomb[j] * lw[j * HOUT + tid];
            mids[tid] = fmaxf(a, 0.f);
        }
        __syncthreads();
        // next FastGTN init: H0'[c,row,h] = sum_k mid[k] * Ws_next[c,k,h]
        float a = 0.f;
        const float* w = Wsn + c * HOUT * HOUT + lane;
#pragma unroll 8
        for (int k = 0; k < HOUT; ++k) a += mids[k] * w[k * HOUT];
        int o = (c * N_NODES + row) * HOUT + lane;
        outp[o] = a;
        ((unsigned short*)out16)[o] = f2bf(a);
    }
}

extern "C" void kernel_launch(void* const* d_in, const int* in_sizes, int n_in,
                              void* d_out, int out_size, void* d_ws, size_t ws_size,
                              hipStream_t stream) {
    const int*   ei  = (const int*)d_in[0];
    const float* ew  = (const float*)d_in[1];
    const float* X   = (const float*)d_in[2];
    const float* Ws1 = (const float*)d_in[3];
    const float* cw1 = (const float*)d_in[4];
    const float* lw1 = (const float*)d_in[5];
    const float* lb1 = (const float*)d_in[6];
    const float* Ws2 = (const float*)d_in[7];
    const float* cw2 = (const float*)d_in[8];
    const float* lw2 = (const float*)d_in[9];
    const float* lb2 = (const float*)d_in[10];
    float* outp = (float*)d_out;

    char* ws = (char*)d_ws;
    size_t off = 0;
    auto alloc = [&](size_t bytes) -> void* {
        void* p = ws + off;
        off += (bytes + 255) & ~size_t(255);
        return p;
    };
    int*      cursor = (int*)alloc(N_NODES * 4);
    uint2*    edges  = (uint2*)alloc((size_t)N_NODES * CAP * 8);
    float*    H0a    = (float*)alloc((size_t)2 * N_NODES * HOUT * 4);
    unsigned* H0a16  = (unsigned*)alloc((size_t)2 * N_NODES * HOUT * 2);
    unsigned* Ha16   = (unsigned*)alloc((size_t)2 * N_NODES * HOUT * 2);
    float*    H0b    = (float*)alloc((size_t)2 * N_NODES * HOUT * 4);
    unsigned* H0b16  = (unsigned*)alloc((size_t)2 * N_NODES * HOUT * 2);

    // FastGTN #1
    zinit_kernel  <<<2048, 256, 0, stream>>>(X, Ws1, H0a, H0a16, cursor);
    scatter_kernel<<<NE_TOT / 1024, 256, 0, stream>>>(ei, ew, cursor, edges);
    spmm_kernel   <<<2048, 256, 0, stream>>>(cursor, edges, H0a16, Ha16, cw1);
    tail_kernel<false><<<N_NODES, 128, 0, stream>>>(
        cursor, edges, Ha16, H0a, cw1, lw1, lb1, Ws2, H0b, H0b16);

    // FastGTN #2
    spmm_kernel   <<<2048, 256, 0, stream>>>(cursor, edges, H0b16, Ha16, cw2);
    tail_kernel<true><<<N_NODES, 128, 0, stream>>>(
        cursor, edges, Ha16, H0b, cw2, lw2, lb2, nullptr, outp, nullptr);
}